// Round 14
// baseline (1161.912 us; speedup 1.0000x reference)
//
#include <hip/hip_runtime.h>

#define NN 2048
#define NE 32768
#define NG 64
#define DINJ 240
#define DEMB 480
#define DFEAT 512
#define MAXDEG 192

typedef unsigned short ushort_t;
typedef __attribute__((ext_vector_type(8))) short short8;
typedef __attribute__((ext_vector_type(4))) float floatx4;
typedef __attribute__((ext_vector_type(4))) unsigned short ushortx4;

__device__ __forceinline__ float b2f(ushort_t u){
  union { unsigned u; float f; } x; x.u = ((unsigned)u) << 16; return x.f;
}
__device__ __forceinline__ ushort_t f2b(float f){
  union { float f; unsigned u; } x; x.f = f;
  unsigned r = x.u + 0x7FFFu + ((x.u >> 16) & 1u);
  return (ushort_t)(r >> 16);
}
__device__ __forceinline__ float wredsum(float v){
  #pragma unroll
  for (int o = 32; o > 0; o >>= 1) v += __shfl_xor(v, o, 64);
  return v;
}
__device__ __forceinline__ float silu_f(float x){ return x / (1.f + __expf(-x)); }

// XCD-aware bijective block swizzle (T1, m204): per-XCD contiguous band of
// B column-panels -> per-XCD working set fits the 4MB private L2.
// (round 5: -63us, confirmed mechanism)
__device__ __forceinline__ void xcd_swizzle(int& bx, int& by){
  int gx = gridDim.x, gy = gridDim.y;
  int nb = gx*gy;
  int lb = blockIdx.y*gx + blockIdx.x;
  int q = nb >> 3, r = nb & 7;
  int xcd = lb & 7, pos = lb >> 3;
  int nlb = (xcd < r) ? (xcd*(q+1) + pos) : (r*(q+1) + (xcd - r)*q + pos);
  bx = nlb / gy;
  by = nlb - bx*gy;
}

// ------- input dtype detection (also zeroes the CSR counts buffer) ----------
__global__ void detect_kernel(const ushort_t* __restrict__ probe, int* flag,
                              int* __restrict__ counts){
  __shared__ int c;
  if (threadIdx.x == 0) c = 0;
  __syncthreads();
  #pragma unroll
  for (int r = 0; r < 8; ++r) counts[threadIdx.x*8 + r] = 0;
  ushort_t u = probe[2*threadIdx.x];
  int e = (u >> 7) & 0xFF;
  int plausible = (u == 0) || (e >= 100 && e <= 140);
  atomicAdd(&c, plausible);
  __syncthreads();
  if (threadIdx.x == 0) *flag = (c >= 192) ? 0 : 1;
}

// -------- convert small float inputs -> internal FP32 (exact either way) ----
// Round 14: 4-wide vectorized (all n divisible by 4).
struct CDesc { const void* src; float* dst; int n; };
struct CDescArr { CDesc d[11]; };
__global__ __launch_bounds__(256) void convert_inputs(CDescArr ca, const int* __restrict__ flag){
  CDesc cd = ca.d[blockIdx.y];
  int isf32 = *flag;
  int nv = cd.n >> 2;
  for (int v = blockIdx.x*256 + threadIdx.x; v < nv; v += gridDim.x*256){
    floatx4 o;
    if (isf32){
      o = ((const floatx4*)cd.src)[v];
    } else {
      ushortx4 u = ((const ushortx4*)cd.src)[v];
      o[0] = b2f(u[0]); o[1] = b2f(u[1]); o[2] = b2f(u[2]); o[3] = b2f(u[3]);
    }
    ((floatx4*)cd.dst)[v] = o;
  }
}

// --- LDS-tiled weight transpose: src (K x M row-major) -> dst (Mpad x Kpad) --
// (Bl low-order output retired round 9 -- only the bf16-high part is stored.)
struct TDesc { const void* src; ushort_t* dh; int K; int M; int Kpad; int Mpad; int eoff; };
struct TDescArr { TDesc d[37]; };
__global__ __launch_bounds__(256) void transpose_all(TDescArr ta, const int* __restrict__ flag){
  TDesc td = ta.d[blockIdx.z];
  int k0 = blockIdx.x*32, m0 = blockIdx.y*32;
  if (k0 >= td.Kpad || m0 >= td.Mpad) return;
  int isf32 = *flag;
  __shared__ float lds[32*33];
  int tx = threadIdx.x & 31, ty = threadIdx.x >> 5;
  #pragma unroll
  for (int r = 0; r < 4; ++r){
    int kl = ty + r*8;
    int k = k0 + kl, mm = m0 + tx;
    float x = 0.f;
    if (k < td.K && mm < td.M){
      size_t si = (size_t)td.eoff + (size_t)k*td.M + mm;
      x = isf32 ? ((const float*)td.src)[si] : b2f(((const ushort_t*)td.src)[si]);
    }
    lds[kl*33 + tx] = x;
  }
  __syncthreads();
  #pragma unroll
  for (int r = 0; r < 4; ++r){
    int nl = ty + r*8;
    int n = m0 + nl, k = k0 + tx;
    if (n < td.Mpad && k < td.Kpad){
      float x = lds[tx*33 + nl];
      size_t di = (size_t)n*td.Kpad + k;
      td.dh[di] = f2b(x);
    }
  }
}

// ---- fused per-edge setup: spherical harmonics + RBF projections + CSR hist.
__global__ __launch_bounds__(128) void edge_all_kernel(
    const float* __restrict__ pos,
    const int* __restrict__ esrc, const int* __restrict__ edst,
    const float* __restrict__ degWr,
    const float* __restrict__ b0Wr, const float* __restrict__ bmWr,
    const float* __restrict__ bfWr,
    float* __restrict__ sh_out, float* __restrict__ t9,
    float* __restrict__ r_all, int* __restrict__ counts){
  __shared__ float w9L[128*9];
  __shared__ float w24L[128*24];
  int t = threadIdx.x;
  for (int i = t; i < 128*9; i += 128)  w9L[i]  = degWr[i];
  for (int i = t; i < 128*24; i += 128){
    int k = i / 24, o = i - k*24;
    int slot = o >> 2, h = o & 3;
    const float* Wr = (slot == 0) ? b0Wr : ((slot <= 4) ? bmWr + (size_t)(slot-1)*512 : bfWr);
    w24L[i] = Wr[k*4+h];
  }
  __syncthreads();
  int e = blockIdx.x*128 + t; if (e >= NE) return;
  int s = esrc[e], d = edst[e];
  atomicAdd(&counts[d], 1);
  float x = pos[s*3+0] - pos[d*3+0];
  float y = pos[s*3+1] - pos[d*3+1];
  float z = pos[s*3+2] - pos[d*3+2];
  float dd = sqrtf(x*x + y*y + z*z + 1e-12f);
  float ix = x/dd, iy = y/dd, iz = z/dd;
  const float s3 = 1.7320508075688772f, s15 = 3.872983346207417f, s5 = 2.23606797749979f;
  float sh[9];
  sh[0] = 1.f; sh[1] = s3*ix; sh[2] = s3*iy; sh[3] = s3*iz;
  sh[4] = s15*ix*iy; sh[5] = s15*iy*iz; sh[6] = 0.5f*s5*(3.f*iz*iz - 1.f);
  sh[7] = s15*ix*iz; sh[8] = 0.5f*s15*(ix*ix - iy*iy);
  #pragma unroll
  for (int j = 0; j < 9; ++j) sh_out[(size_t)e*9+j] = sh[j];
  float t9a[9], ga[24];
  #pragma unroll
  for (int j = 0; j < 9; ++j) t9a[j] = 0.f;
  #pragma unroll
  for (int o = 0; o < 24; ++o) ga[o] = 0.f;
  for (int k = 0; k < 128; ++k){
    float c = (float)k * (5.0f/127.0f);
    float u = (dd - c) * (128.0f/5.0f);
    float rb = __expf(-0.5f*u*u);
    const float* w9  = w9L + k*9;
    const float* w24 = w24L + k*24;
    #pragma unroll
    for (int j = 0; j < 9; ++j) t9a[j] += rb*w9[j];
    #pragma unroll
    for (int o = 0; o < 24; ++o) ga[o] += rb*w24[o];
  }
  #pragma unroll
  for (int j = 0; j < 9; ++j) t9[(size_t)e*9+j] = sh[j]*silu_f(t9a[j]);
  #pragma unroll
  for (int slot = 0; slot < 6; ++slot){
    floatx4 rv;
    rv[0] = silu_f(ga[slot*4+0]);
    rv[1] = silu_f(ga[slot*4+1]);
    rv[2] = silu_f(ga[slot*4+2]);
    rv[3] = silu_f(ga[slot*4+3]);
    *(floatx4*)&r_all[((size_t)slot*NE + e)*4] = rv;
  }
}

// ---------------- CSR build ----------------
__global__ __launch_bounds__(1024) void scan_kernel(const int* __restrict__ counts,
                                                    int* rowptr, int* cursor,
                                                    float* __restrict__ gsum){
  __shared__ int s[1024];
  int t = threadIdx.x;
  if (t < 64) gsum[t] = 0.f;
  int c0 = counts[2*t], c1 = counts[2*t+1];
  s[t] = c0 + c1;
  __syncthreads();
  for (int off = 1; off < 1024; off <<= 1){
    int v = (t >= off) ? s[t-off] : 0;
    __syncthreads();
    s[t] += v;
    __syncthreads();
  }
  int excl = s[t] - (c0 + c1);
  rowptr[2*t]   = excl;       cursor[2*t]   = excl;
  rowptr[2*t+1] = excl + c0;  cursor[2*t+1] = excl + c0;
  if (t == 1023) rowptr[2048] = s[1023];
}
__global__ void scatter_kernel(const int* __restrict__ edst, int* cursor, int* perm){
  int e = blockIdx.x*256 + threadIdx.x; if (e >= NE) return;
  int p = atomicAdd(&cursor[edst[e]], 1);
  perm[p] = e;
}

// -- inj = atom_table[node_atom] + (sum_e t9) @ degWsh / 16; also zeroes z0 ---
__global__ __launch_bounds__(64) void inj_kernel(const float* __restrict__ t9,
    const int* __restrict__ rowptr, const int* __restrict__ perm,
    const int* __restrict__ node_atom, const float* __restrict__ atom_table,
    const float* __restrict__ degWsh, float* __restrict__ inj,
    float* __restrict__ z0){
  int i = blockIdx.x; int lane = threadIdx.x;
  int b = rowptr[i], e = rowptr[i+1];
  floatx4* z4 = (floatx4*)(z0 + (size_t)i*480);
  #pragma unroll
  for (int v = lane; v < 120; v += 64) z4[v] = (floatx4){0,0,0,0};
  float T[9];
  #pragma unroll
  for (int j = 0; j < 9; ++j) T[j] = 0.f;
  for (int idx = b; idx < e; ++idx){
    int ed = perm[idx];
    #pragma unroll
    for (int j = 0; j < 9; ++j) T[j] += t9[(size_t)ed*9+j];
  }
  int a = node_atom[i];
  if (lane < 60){
    const floatx4* tb4 = (const floatx4*)(atom_table + (size_t)a*DINJ);
    const floatx4* w4  = (const floatx4*)degWsh;
    floatx4 s = {0,0,0,0};
    #pragma unroll
    for (int j = 0; j < 9; ++j){
      floatx4 wv = w4[j*60 + lane];
      s[0] += T[j]*wv[0]; s[1] += T[j]*wv[1];
      s[2] += T[j]*wv[2]; s[3] += T[j]*wv[3];
    }
    floatx4 tv = tb4[lane];
    floatx4 o;
    o[0] = tv[0] + s[0]*(1.0f/16.0f);
    o[1] = tv[1] + s[1]*(1.0f/16.0f);
    o[2] = tv[2] + s[2]*(1.0f/16.0f);
    o[3] = tv[3] + s[3]*(1.0f/16.0f);
    *(floatx4*)(inj + (size_t)i*DINJ + lane*4) = o;
  }
}

// ------- LayerNorm: one wave per row, 4 rows per block. ----------------------
__global__ __launch_bounds__(256) void ln_kernel(const float* __restrict__ in, int D,
                                                 int Kpad, ushort_t* __restrict__ oh){
  int i = blockIdx.x*4 + (threadIdx.x >> 6);
  int lane = threadIdx.x & 63;
  const float4* row = (const float4*)(in + (size_t)i*D);
  int nv = D >> 2;
  float4 x0 = row[lane];
  bool h1 = (lane + 64)  < nv;
  bool h2 = (lane + 128) < nv;
  float4 x1 = {0,0,0,0}; if (h1) x1 = row[lane+64];
  float4 x2 = {0,0,0,0}; if (h2) x2 = row[lane+128];
  float s  = x0.x+x0.y+x0.z+x0.w + x1.x+x1.y+x1.z+x1.w + x2.x+x2.y+x2.z+x2.w;
  float sq = x0.x*x0.x+x0.y*x0.y+x0.z*x0.z+x0.w*x0.w
           + x1.x*x1.x+x1.y*x1.y+x1.z*x1.z+x1.w*x1.w
           + x2.x*x2.x+x2.y*x2.y+x2.z*x2.z+x2.w*x2.w;
  s = wredsum(s); sq = wredsum(sq);
  float mu = s / (float)D;
  float var = fmaxf(sq / (float)D - mu*mu, 0.f);
  float rs = rsqrtf(var + 1e-6f);
  ushort_t* ohrow = oh + (size_t)i*Kpad;
  auto st = [&](int v, float4 x){
    ushortx4 o;
    o[0] = f2b((x.x-mu)*rs); o[1] = f2b((x.y-mu)*rs);
    o[2] = f2b((x.z-mu)*rs); o[3] = f2b((x.w-mu)*rs);
    *(ushortx4*)(ohrow + (size_t)v*4) = o;
  };
  st(lane, x0);
  if (h1) st(lane+64, x1);
  if (h2) st(lane+128, x2);
  for (int d = D + lane; d < Kpad; d += 64) ohrow[d] = 0;
}

// ------- LayerNorm over concat [z(480) | inj(240)] -> 736-padded bf16 --------
__global__ __launch_bounds__(256) void ln_cat_kernel(const float* __restrict__ z,
    const float* __restrict__ inj, ushort_t* __restrict__ oh){
  int i = blockIdx.x*4 + (threadIdx.x >> 6);
  int lane = threadIdx.x & 63;
  const float4* zr = (const float4*)(z + (size_t)i*480);     // 120 float4
  const float4* ir = (const float4*)(inj + (size_t)i*240);   // 60 float4
  auto ld = [&](int v) -> float4 { return (v < 120) ? zr[v] : ir[v-120]; };
  float4 x0 = ld(lane);
  float4 x1 = ld(lane + 64);
  bool h2 = (lane + 128) < 180;
  float4 x2 = {0,0,0,0}; if (h2) x2 = ld(lane+128);
  float s  = x0.x+x0.y+x0.z+x0.w + x1.x+x1.y+x1.z+x1.w + x2.x+x2.y+x2.z+x2.w;
  float sq = x0.x*x0.x+x0.y*x0.y+x0.z*x0.z+x0.w*x0.w
           + x1.x*x1.x+x1.y*x1.y+x1.z*x1.z+x1.w*x1.w
           + x2.x*x2.x+x2.y*x2.y+x2.z*x2.z+x2.w*x2.w;
  s = wredsum(s); sq = wredsum(sq);
  float mu = s * (1.0f/720.0f);
  float var = fmaxf(sq * (1.0f/720.0f) - mu*mu, 0.f);
  float rs = rsqrtf(var + 1e-6f);
  ushort_t* ohrow = oh + (size_t)i*736;
  auto st = [&](int v, float4 x){
    ushortx4 o;
    o[0] = f2b((x.x-mu)*rs); o[1] = f2b((x.y-mu)*rs);
    o[2] = f2b((x.z-mu)*rs); o[3] = f2b((x.w-mu)*rs);
    *(ushortx4*)(ohrow + (size_t)v*4) = o;
  };
  st(lane, x0);
  st(lane+64, x1);
  if (h2) st(lane+128, x2);
  for (int d = 720 + lane; d < 736; d += 64) ohrow[d] = 0;
}

// ---- shared MFMA ring: compile-time COUNT/BASE keep the ring in registers ---
struct Frag { short8 A0, A1, B0h, B1h; };
template<int COUNT, int BASE>
__device__ __forceinline__ void mfma_ring(
    const ushort_t* __restrict__ A, size_t a0, size_t a1,
    const ushort_t* __restrict__ BTh, size_t b0, size_t b1,
    floatx4& acc00, floatx4& acc01, floatx4& acc10, floatx4& acc11){
  constexpr int DEPTH = 4;
  auto loadF = [&](int s) -> Frag {
    Frag f;
    size_t o = (size_t)(BASE + s)*32;
    f.A0  = *(const short8*)(A   + a0 + o);
    f.A1  = *(const short8*)(A   + a1 + o);
    f.B0h = *(const short8*)(BTh + b0 + o);
    f.B1h = *(const short8*)(BTh + b1 + o);
    return f;
  };
  Frag ring[DEPTH];
  #pragma unroll
  for (int d = 0; d < DEPTH; ++d) ring[d] = loadF(d < COUNT ? d : COUNT-1);
  #pragma unroll
  for (int s = 0; s < COUNT; ++s){
    Frag cur = ring[s % DEPTH];
    if (s + DEPTH < COUNT) ring[s % DEPTH] = loadF(s + DEPTH);
    acc00 = __builtin_amdgcn_mfma_f32_16x16x32_bf16(cur.A0, cur.B0h, acc00, 0, 0, 0);
    acc01 = __builtin_amdgcn_mfma_f32_16x16x32_bf16(cur.A0, cur.B1h, acc01, 0, 0, 0);
    acc10 = __builtin_amdgcn_mfma_f32_16x16x32_bf16(cur.A1, cur.B0h, acc10, 0, 0, 0);
    acc11 = __builtin_amdgcn_mfma_f32_16x16x32_bf16(cur.A1, cur.B1h, acc11, 0, 0, 0);
  }
}

// -- MFMA GEMM: C = A * Bh^T (Bl split fully retired round 9). ----------------
// flags: 1=silu, 2=add residual, 4=bf16 out, 8=residual is concat(R 480, R2 240)
//        16=qkv split-out: col<960 -> Cf (f32, ld 960), col>=960 -> Cb (bf16, ld 480)
template<int KPAD>
__global__ __launch_bounds__(256) void gemm_bt(
    const ushort_t* __restrict__ A, const ushort_t* __restrict__ BTh,
    int N, int ldc,
    float* __restrict__ Cf, ushort_t* __restrict__ Cb,
    const float* __restrict__ R, const float* __restrict__ R2, int flags){
  int bx, by; xcd_swizzle(bx, by);
  int lane = threadIdx.x & 63, wave = threadIdx.x >> 6;
  int row0 = by*64 + (wave>>1)*32;
  int col0 = bx*64 + (wave&1)*32;
  int m = lane & 15, q4 = lane >> 4;
  size_t a0 = (size_t)(row0+m)*KPAD + q4*8;
  size_t a1 = a0 + (size_t)16*KPAD;
  size_t b0 = (size_t)(col0+m)*KPAD + q4*8;
  size_t b1 = b0 + (size_t)16*KPAD;
  floatx4 acc00 = {0,0,0,0}, acc01 = {0,0,0,0}, acc10 = {0,0,0,0}, acc11 = {0,0,0,0};
  constexpr int steps = KPAD >> 5;
  mfma_ring<steps, 0>(A, a0, a1, BTh, b0, b1, acc00, acc01, acc10, acc11);
  #pragma unroll
  for (int rr = 0; rr < 2; ++rr){
    #pragma unroll
    for (int cc = 0; cc < 2; ++cc){
      int col = col0 + cc*16 + m;
      if (col >= N) continue;
      floatx4 acc = rr ? (cc ? acc11 : acc10) : (cc ? acc01 : acc00);
      int rowb = row0 + rr*16 + q4*4;
      #pragma unroll
      for (int r = 0; r < 4; ++r){
        int row = rowb + r;
        float v = acc[r];
        if (flags & 16){
          if (col < 960) Cf[(size_t)row*960 + col] = v;
          else           Cb[(size_t)row*480 + (col - 960)] = f2b(v);
          continue;
        }
        size_t idx = (size_t)row*ldc + col;
        if (flags & 2){
          if (flags & 8)
            v += (col < 480) ? R[(size_t)row*480 + col] : R2[(size_t)row*240 + (col-480)];
          else
            v += R[idx];
        }
        if (flags & 1) v = silu_f(v);
        if (flags & 4) Cb[idx] = f2b(v);
        else           Cf[idx] = v;
      }
    }
  }
}

// -- 8-wave split-K variant for small-N GEMMs. ---
template<int KPAD>
__global__ __launch_bounds__(512) void gemm_bt8(
    const ushort_t* __restrict__ A, const ushort_t* __restrict__ BTh,
    int N, int ldc,
    float* __restrict__ Cf, ushort_t* __restrict__ Cb,
    const float* __restrict__ R, const float* __restrict__ R2, int flags){
  __shared__ float accL[4][4][256];
  int bx, by; xcd_swizzle(bx, by);
  int lane = threadIdx.x & 63, wave = threadIdx.x >> 6;
  int half = wave >> 2, w4 = wave & 3;
  int row0 = by*64 + (w4>>1)*32;
  int col0 = bx*64 + (w4&1)*32;
  int m = lane & 15, q4 = lane >> 4;
  size_t a0 = (size_t)(row0+m)*KPAD + q4*8;
  size_t a1 = a0 + (size_t)16*KPAD;
  size_t b0 = (size_t)(col0+m)*KPAD + q4*8;
  size_t b1 = b0 + (size_t)16*KPAD;
  floatx4 acc00 = {0,0,0,0}, acc01 = {0,0,0,0}, acc10 = {0,0,0,0}, acc11 = {0,0,0,0};
  constexpr int steps = KPAD >> 5;
  constexpr int S0 = (steps + 1) >> 1;
  constexpr int S1 = steps - S0;
  if (half == 0)
    mfma_ring<S0, 0 >(A, a0, a1, BTh, b0, b1, acc00, acc01, acc10, acc11);
  else
    mfma_ring<S1, S0>(A, a0, a1, BTh, b0, b1, acc00, acc01, acc10, acc11);
  if (half == 1){
    *(floatx4*)&accL[w4][0][lane*4] = acc00;
    *(floatx4*)&accL[w4][1][lane*4] = acc01;
    *(floatx4*)&accL[w4][2][lane*4] = acc10;
    *(floatx4*)&accL[w4][3][lane*4] = acc11;
  }
  __syncthreads();
  if (half == 1) return;
  acc00 += *(const floatx4*)&accL[w4][0][lane*4];
  acc01 += *(const floatx4*)&accL[w4][1][lane*4];
  acc10 += *(const floatx4*)&accL[w4][2][lane*4];
  acc11 += *(const floatx4*)&accL[w4][3][lane*4];
  #pragma unroll
  for (int rr = 0; rr < 2; ++rr){
    #pragma unroll
    for (int cc = 0; cc < 2; ++cc){
      int col = col0 + cc*16 + m;
      if (col >= N) continue;
      floatx4 acc = rr ? (cc ? acc11 : acc10) : (cc ? acc01 : acc00);
      int rowb = row0 + rr*16 + q4*4;
      #pragma unroll
      for (int r = 0; r < 4; ++r){
        int row = rowb + r;
        float v = acc[r];
        size_t idx = (size_t)row*ldc + col;
        if (flags & 2){
          if (flags & 8)
            v += (col < 480) ? R[(size_t)row*480 + col] : R2[(size_t)row*240 + (col-480)];
          else
            v += R[idx];
        }
        if (flags & 1) v = silu_f(v);
        if (flags & 4) Cb[idx] = f2b(v);
        else           Cf[idx] = v;
      }
    }
  }
}

// ------- fused per-node attention: logits + softmax + aggregation ------------
// qk: f32 [NN][960] (q 0..479, k 480..959); vb: bf16 [NN][480]
// K stays f32 (round 6: bf16-K trades in-flight loads for unpack VALU -> slower).
// sh rows + r gates staged to LDS (round 8: helped).
// Logits: 2 lanes per (edge,head) (round 5: won; round 10's 4-lane split
// REGRESSED -- per-lane in-flight loads are the currency, not lane count).
// Round 14: V-aggregation 2-way edge unroll, tested ALONE (unbundled from
// the regressing round-10 change set).
__global__ __launch_bounds__(256) void node_attn_kernel(
    const float* __restrict__ qk, const ushort_t* __restrict__ vb,
    const float* __restrict__ sh,
    const float* __restrict__ Wsh, const float* __restrict__ r_slot,
    const int* __restrict__ rowptr, const int* __restrict__ perm,
    const int* __restrict__ esrc, ushort_t* __restrict__ aggh){
  int i = blockIdx.x; int t = threadIdx.x;
  int lane = t & 63, w = t >> 6;
  int b = rowptr[i]; int deg = min(rowptr[i+1] - b, MAXDEG);
  __shared__ float qL[480];
  __shared__ float PqL[36];
  __shared__ float logitL[MAXDEG*4];
  __shared__ float rL[MAXDEG*4];
  __shared__ float shL[MAXDEG*9];
  __shared__ int eL[MAXDEG], srcL[MAXDEG];
  __shared__ float S[36];
  __shared__ float mxs[4], dens[4];
  if (t < 120) ((float4*)qL)[t] = ((const float4*)(qk + (size_t)i*960))[t];
  for (int idx = t; idx < deg; idx += 256){
    int e = perm[b+idx];
    eL[idx] = e;
    srcL[idx] = esrc[e];
  }
  __syncthreads();
  // stage sh rows (deg x 9) and r gates (deg x 4) into LDS
  for (int j = t; j < deg*9; j += 256){
    int idx = j/9;
    shL[j] = sh[(size_t)eL[idx]*9 + (j - idx*9)];
  }
  for (int j = t; j < deg*4; j += 256){
    rL[j] = r_slot[(size_t)eL[j>>2]*4 + (j&3)];
  }
  // PqL[h*9+j] = q_h . Wsh[j, h*120..]; 4 lanes per output, quad shuffle reduce
  if (t < 144){
    int o = t >> 2;
    int h = o/9, j = o - h*9;
    int kq = (t & 3)*30;
    const float* ws = Wsh + (size_t)j*DEMB + h*120 + kq;
    const float* qh = qL + h*120 + kq;
    float p = 0.f;
    #pragma unroll
    for (int k = 0; k < 30; ++k) p += qh[k]*ws[k];
    p += __shfl_xor(p, 1, 64);
    p += __shfl_xor(p, 2, 64);
    if ((t & 3) == 0) PqL[o] = p;
  }
  __syncthreads();
  const float inv = 0.091287092917527686f;
  // logits: 2 lanes per (edge,head) -> 32 edges/pass, 15 float4 each, pair-reduce
  for (int base = 0; base < deg; base += 32){
    int idx = base + (t >> 3);
    if (idx < deg){
      int h = (t >> 1) & 3;
      int hs = t & 1;
      int s = srcL[idx];
      const float4* kk = (const float4*)(qk + (size_t)s*960 + 480 + h*120) + hs*15;
      const float4* qq = (const float4*)(qL + h*120) + hs*15;
      float p = 0.f;
      #pragma unroll
      for (int it = 0; it < 15; ++it){
        float4 a = qq[it], bb = kk[it];
        p += a.x*bb.x + a.y*bb.y + a.z*bb.z + a.w*bb.w;
      }
      p += __shfl_xor(p, 1, 64);
      if (hs == 0){
        float mmq = 0.f;
        const float* she = shL + idx*9;
        #pragma unroll
        for (int j = 0; j < 9; ++j) mmq += she[j]*PqL[h*9+j];
        logitL[idx*4+h] = rL[idx*4+h]*(p + mmq)*inv;
      }
    }
  }
  __syncthreads();
  float mx = -1e30f;
  for (int idx = lane; idx < deg; idx += 64) mx = fmaxf(mx, logitL[idx*4+w]);
  #pragma unroll
  for (int o = 32; o > 0; o >>= 1) mx = fmaxf(mx, __shfl_xor(mx, o, 64));
  if (deg == 0) mx = 0.f;
  float den = 0.f;
  for (int idx = lane; idx < deg; idx += 64) den += __expf(logitL[idx*4+w]-mx);
  den = wredsum(den) + 1e-9f;
  if (lane == 0){ mxs[w] = mx; dens[w] = den; }
  __syncthreads();
  for (int j = t; j < deg*4; j += 256){
    int h = j & 3;
    logitL[j] = __expf(logitL[j]-mxs[h]) / dens[h] * rL[j];
  }
  __syncthreads();
  float a0 = 0.f, a1 = 0.f;
  int d0 = 2*t, h2 = d0/120;
  if (t >= 240){
    for (int o = t - 240; o < 36; o += 16){
      int h = o/9, j = o - h*9;
      float a = 0.f;
      for (int idx = 0; idx < deg; ++idx)
        a += logitL[idx*4+h]*shL[idx*9+j];
      S[o] = a;
    }
  } else {
    // 2-way edge unroll: doubles independent scattered V loads in flight
    int idx = 0;
    for (; idx + 1 < deg; idx += 2){
      float w0 = logitL[idx*4+h2], w1 = logitL[(idx+1)*4+h2];
      unsigned v0 = *(const unsigned*)(vb + (size_t)srcL[idx]*480 + d0);
      unsigned v1 = *(const unsigned*)(vb + (size_t)srcL[idx+1]*480 + d0);
      a0 += w0*b2f((ushort_t)(v0 & 0xFFFFu)) + w1*b2f((ushort_t)(v1 & 0xFFFFu));
      a1 += w0*b2f((ushort_t)(v0 >> 16))     + w1*b2f((ushort_t)(v1 >> 16));
    }
    if (idx < deg){
      float wgt = logitL[idx*4+h2];
      unsigned vv = *(const unsigned*)(vb + (size_t)srcL[idx]*480 + d0);
      a0 += wgt*b2f((ushort_t)(vv & 0xFFFFu));
      a1 += wgt*b2f((ushort_t)(vv >> 16));
    }
  }
  __syncthreads();
  if (t < 240){
    float mm0 = 0.f, mm1 = 0.f;
    #pragma unroll
    for (int j = 0; j < 9; ++j){
      mm0 += S[h2*9+j]*Wsh[j*DEMB + d0];
      mm1 += S[h2*9+j]*Wsh[j*DEMB + d0 + 1];
    }
    aggh[(size_t)i*DEMB + d0]     = f2b(a0 + mm0);
    aggh[(size_t)i*DEMB + d0 + 1] = f2b(a1 + mm1);
  }
}

// ---------------- head ----------------
__global__ __launch_bounds__(256) void head_dot_kernel(const ushort_t* __restrict__ g1h,
    const float* __restrict__ hW2, const int* __restrict__ batch, float* gsum){
  int i = blockIdx.x*4 + (threadIdx.x >> 6);
  int lane = threadIdx.x & 63;
  const ushortx4* gr = (const ushortx4*)(g1h + (size_t)i*DFEAT);
  const float4* wv = (const float4*)hW2;
  float s = 0.f;
  #pragma unroll
  for (int v = 0; v < 2; ++v){
    int idx = lane + v*64;
    ushortx4 g = gr[idx];
    float4 ww = wv[idx];
    s += b2f(g[0])*ww.x + b2f(g[1])*ww.y + b2f(g[2])*ww.z + b2f(g[3])*ww.w;
  }
  s = wredsum(s);
  if (lane == 0) atomicAdd(&gsum[batch[i]], s);
}
__global__ void finalize_kernel(const float* __restrict__ gsum,
                                const int* __restrict__ flag, void* out){
  int g = threadIdx.x;
  if (g < NG){
    float v = gsum[g] * 0.17677669529663687f; // 1/sqrt(32)
    if (*flag) ((float*)out)[g] = v;
    else       ((ushort_t*)out)[g] = f2b(v);
  }
}

// =====================================================================
extern "C" void kernel_launch(void* const* d_in, const int* in_sizes, int n_in,
                              void* d_out, int out_size, void* d_ws, size_t ws_size,
                              hipStream_t stream) {
  (void)in_sizes; (void)n_in; (void)out_size; (void)ws_size;
  const void* pos        = d_in[0];
  const int*  node_atom  = (const int*)d_in[1];
  const int*  esrc       = (const int*)d_in[2];
  const int*  edst       = (const int*)d_in[3];
  const int*  batch      = (const int*)d_in[4];
  const void* atom_table = d_in[5];
  const void* degWr      = d_in[6];
  const void* degWsh     = d_in[7];
  const void* b0_Wq  = d_in[8];
  const void* b0_Wk  = d_in[9];
  const void* b0_Wv  = d_in[10];
  const void* b0_Wsh = d_in[11];
  const void* b0_Wr  = d_in[12];
  const void* b0_Wo  = d_in[13];
  const void* b0_F1  = d_in[14];
  const void* b0_F2  = d_in[15];
  const void* bm_Wq  = d_in[16];
  const void* bm_Wk  = d_in[17];
  const void* bm_Wv  = d_in[18];
  const void* bm_Wsh = d_in[19];
  const void* bm_Wr  = d_in[20];
  const void* bm_Wo  = d_in[21];
  const void* bm_F1  = d_in[22];
  const void* bm_F2  = d_in[23];
  const void* bf_Wq  = d_in[24];
  const void* bf_Wk  = d_in[25];
  const void* bf_Wv  = d_in[26];
  const void* bf_Wsh = d_in[27];
  const void* bf_Wr  = d_in[28];
  const void* bf_Wo  = d_in[29];
  const void* bf_F1  = d_in[30];
  const void* bf_F2  = d_in[31];
  const void* hW1    = d_in[32];
  const void* hW2    = d_in[33];

  char* bws = (char*)d_ws;
  size_t off = 0;
  auto alloc = [&](size_t bytes) -> void* {
    void* p = bws + off;
    off += (bytes + 255) & ~(size_t)255;
    return p;
  };
  int* dflag   = (int*)alloc(256);
  float* sh_f  = (float*)alloc((size_t)NE*9*4);
  float* t9    = (float*)alloc((size_t)NE*9*4);
  int* counts  = (int*)alloc(2048*4);
  int* rowptr  = (int*)alloc(2049*4);
  int* cursor  = (int*)alloc(2048*4);
  int* perm    = (int*)alloc((size_t)NE*4);
  float* injb  = (float*)alloc((size_t)NN*DINJ*4);
  float* zA    = (float*)alloc((size_t)NN*512*4);
  float* zB    = (float*)alloc((size_t)NN*512*4);
  ushort_t* xlnh = (ushort_t*)alloc((size_t)NN*736*2);
  float* qkf   = (float*)alloc((size_t)NN*960*4);
  ushort_t* vbuf = (ushort_t*)alloc((size_t)NN*480*2);
  float* r_all = (float*)alloc((size_t)6*NE*4*4);
  ushort_t* aggh = (ushort_t*)alloc((size_t)NN*DEMB*2);
  float* ybuf  = (float*)alloc((size_t)NN*720*4);
  ushort_t* h1h = (ushort_t*)alloc((size_t)NN*DEMB*2);
  ushort_t* g1h = (ushort_t*)alloc((size_t)NN*DFEAT*2);
  float* gsum  = (float*)alloc(64*4);

  float* pos_c    = (float*)alloc((size_t)NN*3*4);
  float* atom_c   = (float*)alloc((size_t)64*DINJ*4);
  float* degWr_c  = (float*)alloc((size_t)128*9*4);
  float* degWsh_c = (float*)alloc((size_t)9*DINJ*4);
  float* b0_Wsh_c = (float*)alloc((size_t)9*480*4);
  float* b0_Wr_c  = (float*)alloc((size_t)128*4*4);
  float* bm_Wsh_c = (float*)alloc((size_t)4*9*480*4);
  float* bm_Wr_c  = (float*)alloc((size_t)4*128*4*4);
  float* bf_Wsh_c = (float*)alloc((size_t)9*480*4);
  float* bf_Wr_c  = (float*)alloc((size_t)128*4*4);
  float* hW2_c    = (float*)alloc((size_t)512*4);

  auto allocW = [&](size_t elems) -> ushort_t* {
    return (ushort_t*)alloc(elems*2);
  };
  ushort_t *b0_qkvTh = allocW((size_t)1472*736);
  ushort_t *b0_WoTh  = allocW((size_t)768*480);
  ushort_t *b0_F1Th  = allocW((size_t)512*736);
  ushort_t *b0_F2Th  = allocW((size_t)512*480);
  ushort_t *bm_qkvTh[4], *bm_WoTh[4], *bm_F1Th[4], *bm_F2Th[4];
  for (int i = 0; i < 4; ++i){
    bm_qkvTh[i] = allocW((size_t)1472*480);
    bm_WoTh[i]  = allocW((size_t)512*480);
    bm_F1Th[i]  = allocW((size_t)512*480);
    bm_F2Th[i]  = allocW((size_t)512*480);
  }
  ushort_t *bf_qkvTh = allocW((size_t)1472*480);
  ushort_t *bf_WoTh  = allocW((size_t)512*480);
  ushort_t *bf_F1Th  = allocW((size_t)512*480);
  ushort_t *bf_F2Th  = allocW((size_t)512*480);
  ushort_t *hW1Th    = allocW((size_t)512*512);

  detect_kernel<<<1, 256, 0, stream>>>((const ushort_t*)atom_table, dflag, counts);

  CDescArr ca;
  int ci = 0;
  auto addC = [&](const void* s, float* d, int n){
    ca.d[ci].src = s; ca.d[ci].dst = d; ca.d[ci].n = n; ++ci;
  };
  addC(pos, pos_c, NN*3);
  addC(atom_table, atom_c, 64*DINJ);
  addC(degWr, degWr_c, 128*9);
  addC(degWsh, degWsh_c, 9*DINJ);
  addC(b0_Wsh, b0_Wsh_c, 9*480);
  addC(b0_Wr, b0_Wr_c, 128*4);
  addC(bm_Wsh, bm_Wsh_c, 4*9*480);
  addC(bm_Wr, bm_Wr_c, 4*128*4);
  addC(bf_Wsh, bf_Wsh_c, 9*480);
  addC(bf_Wr, bf_Wr_c, 128*4);
  addC(hW2, hW2_c, 512);
  convert_inputs<<<dim3(8, 11), 256, 0, stream>>>(ca, dflag);

  TDescArr ta;
  int ti = 0;
  auto addT = [&](const void* s, ushort_t* dh, int K, int M,
                  int Kp, int Mp, int rowoff, int eo){
    ta.d[ti].src = s;
    ta.d[ti].dh = dh + (size_t)rowoff*Kp;
    ta.d[ti].K = K; ta.d[ti].M = M; ta.d[ti].Kpad = Kp; ta.d[ti].Mpad = Mp;
    ta.d[ti].eoff = eo; ++ti;
  };
  addT(b0_Wq, b0_qkvTh, 720, 480, 736, 480, 0,   0);
  addT(b0_Wk, b0_qkvTh, 720, 480, 736, 480, 480, 0);
  addT(b0_Wv, b0_qkvTh, 720, 480, 736, 512, 960, 0);
  addT(b0_Wo, b0_WoTh,  480, 720, 480, 768, 0,   0);
  addT(b0_F1, b0_F1Th,  720, 480, 736, 512, 0,   0);
  addT(b0_F2, b0_F2Th,  480, 480, 480, 512, 0,   0);
  for (int i = 0; i < 4; ++i){
    int eo = i*480*480;
    addT(bm_Wq, bm_qkvTh[i], 480, 480, 480, 480, 0,   eo);
    addT(bm_Wk, bm_qkvTh[i], 480, 480, 480, 480, 480, eo);
    addT(bm_Wv, bm_qkvTh[i], 480, 480, 480, 512, 960, eo);
    addT(bm_Wo, bm_WoTh[i],  480, 480, 480, 512, 0,   eo);
    addT(bm_F1, bm_F1Th[i],  480, 480, 480, 512, 0,   eo);
    addT(bm_F2, bm_F2Th[i],  480, 480, 480, 512, 0,   eo);
  }
  addT(bf_Wq, bf_qkvTh, 480, 480, 480, 480, 0,   0);
  addT(bf_Wk, bf_qkvTh, 480, 480, 480, 480, 480, 0);
  addT(bf_Wv, bf_qkvTh, 480, 480, 480, 512, 960, 0);
  addT(bf_Wo, bf_WoTh,  480, 480, 480, 512, 0,   0);
  addT(bf_F1, bf_F1Th,  480, 480, 480, 512, 0,   0);
  addT(bf_F2, bf_F2Th,  480, 512, 480, 512, 0,   0);
  addT(hW1,   hW1Th,    512, 512, 512, 512, 0,   0);
  transpose_all<<<dim3(23, 24, 37), 256, 0, stream>>>(ta, dflag);

  edge_all_kernel<<<NE/128, 128, 0, stream>>>(pos_c, esrc, edst, degWr_c,
                                              b0_Wr_c, bm_Wr_c, bf_Wr_c,
                                              sh_f, t9, r_all, counts);

  scan_kernel<<<1, 1024, 0, stream>>>(counts, rowptr, cursor, gsum);
  scatter_kernel<<<NE/256, 256, 0, stream>>>(edst, cursor, perm);

  inj_kernel<<<NN, 64, 0, stream>>>(t9, rowptr, perm, node_atom, atom_c, degWsh_c,
                                    injb, zA);

  auto gemm = [&](const ushort_t* A, const ushort_t* BTh,
                  int N, int Npad, int Kp, int ldc,
                  float* Cf, ushort_t* Cb, const float* R, const float* R2,
                  int flags){
    dim3 g(Npad/64, 32);
    if (Npad <= 768){
      if (Kp == 480)
        gemm_bt8<480><<<g, 512, 0, stream>>>(A, BTh, N, ldc, Cf, Cb, R, R2, flags);
      else if (Kp == 512)
        gemm_bt8<512><<<g, 512, 0, stream>>>(A, BTh, N, ldc, Cf, Cb, R, R2, flags);
      else
        gemm_bt8<736><<<g, 512, 0, stream>>>(A, BTh, N, ldc, Cf, Cb, R, R2, flags);
      return;
    }
    if (Kp == 480)
      gemm_bt<480><<<g, 256, 0, stream>>>(A, BTh, N, ldc, Cf, Cb, R, R2, flags);
    else if (Kp == 512)
      gemm_bt<512><<<g, 256, 0, stream>>>(A, BTh, N, ldc, Cf, Cb, R, R2, flags);
    else
      gemm_bt<736><<<g, 256, 0, stream>>>(A, BTh, N, ldc, Cf, Cb, R, R2, flags);
  };

  struct BW {
    const float *Wsh, *r_slot;
    const ushort_t *qkvTh,*WoTh,*F1Th,*F2Th;
    int Din, Kpad, Dout; bool res;
  };
  auto run_block = [&](const BW& bw, const float* zin, const float* zinj, float* zout){
    if (zinj) ln_cat_kernel<<<NN/4, 256, 0, stream>>>(zin, zinj, xlnh);
    else      ln_kernel<<<NN/4, 256, 0, stream>>>(zin, bw.Din, bw.Kpad, xlnh);
    gemm(xlnh, bw.qkvTh, 1440, 1472, bw.Kpad, 960, qkf, vbuf, nullptr, nullptr, 16);
    node_attn_kernel<<<NN, 256, 0, stream>>>(qkf, vbuf, sh_f, bw.Wsh, bw.r_slot,
                                             rowptr, perm, esrc, aggh);
    int WoNpad = (bw.Din == 720) ? 768 : 512;
    gemm(aggh, bw.WoTh, bw.Din, WoNpad, 480, bw.Din,
         ybuf, nullptr, zin, zinj, zinj ? (2|8) : 2);
    ln_kernel<<<NN/4, 256, 0, stream>>>(ybuf, bw.Din, bw.Kpad, xlnh);
    gemm(xlnh, bw.F1Th, DEMB, 512, bw.Kpad, DEMB, nullptr, h1h, nullptr, nullptr, 1|4);
    gemm(h1h, bw.F2Th, bw.Dout, 512, 480, bw.Dout,
         zout, nullptr, bw.res ? ybuf : nullptr, nullptr, bw.res ? 2 : 0);
  };

  BW b0 = { b0_Wsh_c, r_all + (size_t)0*NE*4,
            b0_qkvTh, b0_WoTh, b0_F1Th, b0_F2Th, 720, 736, 480, false };
  BW bm[4];
  for (int i = 0; i < 4; ++i){
    bm[i] = { bm_Wsh_c + (size_t)i*9*480, r_all + (size_t)(1+i)*NE*4,
              bm_qkvTh[i], bm_WoTh[i], bm_F1Th[i], bm_F2Th[i],
              480, 480, 480, true };
  }
  BW bf = { bf_Wsh_c, r_all + (size_t)5*NE*4,
            bf_qkvTh, bf_WoTh, bf_F1Th, bf_F2Th, 480, 480, 512, false };

  float* z  = zA;
  float* z2 = zB;
  for (int iter = 0; iter < 2; ++iter){
    run_block(b0, z, injb, z2);
    { float* tmp = z; z = z2; z2 = tmp; }
    for (int i = 0; i < 4; ++i){
      run_block(bm[i], z, nullptr, z2);
      { float* tmp = z; z = z2; z2 = tmp; }
    }
  }
  run_block(bf, z, nullptr, z2);
  ln_kernel<<<NN/4, 256, 0, stream>>>(z2, DFEAT, DFEAT, xlnh);
  gemm(xlnh, hW1Th, DFEAT, 512, DFEAT, DFEAT, nullptr, g1h, nullptr, nullptr, 1|4);
  head_dot_kernel<<<NN/4, 256, 0, stream>>>(g1h, hW2_c, batch, gsum);
  finalize_kernel<<<1, 64, 0, stream>>>(gsum, dflag, d_out);
}

// Round 15
// 1125.922 us; speedup vs baseline: 1.0320x; 1.0320x over previous
//
#include <hip/hip_runtime.h>

#define NN 2048
#define NE 32768
#define NG 64
#define DINJ 240
#define DEMB 480
#define DFEAT 512
#define MAXDEG 192

typedef unsigned short ushort_t;
typedef __attribute__((ext_vector_type(8))) short short8;
typedef __attribute__((ext_vector_type(4))) float floatx4;
typedef __attribute__((ext_vector_type(4))) unsigned short ushortx4;

__device__ __forceinline__ float b2f(ushort_t u){
  union { unsigned u; float f; } x; x.u = ((unsigned)u) << 16; return x.f;
}
__device__ __forceinline__ ushort_t f2b(float f){
  union { float f; unsigned u; } x; x.f = f;
  unsigned r = x.u + 0x7FFFu + ((x.u >> 16) & 1u);
  return (ushort_t)(r >> 16);
}
__device__ __forceinline__ float wredsum(float v){
  #pragma unroll
  for (int o = 32; o > 0; o >>= 1) v += __shfl_xor(v, o, 64);
  return v;
}
__device__ __forceinline__ float silu_f(float x){ return x / (1.f + __expf(-x)); }

// XCD-aware bijective block swizzle (T1, m204): per-XCD contiguous band of
// B column-panels -> per-XCD working set fits the 4MB private L2.
// (round 5: -63us, confirmed mechanism)
__device__ __forceinline__ void xcd_swizzle(int& bx, int& by){
  int gx = gridDim.x, gy = gridDim.y;
  int nb = gx*gy;
  int lb = blockIdx.y*gx + blockIdx.x;
  int q = nb >> 3, r = nb & 7;
  int xcd = lb & 7, pos = lb >> 3;
  int nlb = (xcd < r) ? (xcd*(q+1) + pos) : (r*(q+1) + (xcd - r)*q + pos);
  bx = nlb / gy;
  by = nlb - bx*gy;
}

// ------- input dtype detection (also zeroes the CSR counts buffer) ----------
__global__ void detect_kernel(const ushort_t* __restrict__ probe, int* flag,
                              int* __restrict__ counts){
  __shared__ int c;
  if (threadIdx.x == 0) c = 0;
  __syncthreads();
  #pragma unroll
  for (int r = 0; r < 8; ++r) counts[threadIdx.x*8 + r] = 0;
  ushort_t u = probe[2*threadIdx.x];
  int e = (u >> 7) & 0xFF;
  int plausible = (u == 0) || (e >= 100 && e <= 140);
  atomicAdd(&c, plausible);
  __syncthreads();
  if (threadIdx.x == 0) *flag = (c >= 192) ? 0 : 1;
}

// -------- convert small float inputs -> internal FP32 (exact either way) ----
struct CDesc { const void* src; float* dst; int n; };
struct CDescArr { CDesc d[11]; };
__global__ __launch_bounds__(256) void convert_inputs(CDescArr ca, const int* __restrict__ flag){
  CDesc cd = ca.d[blockIdx.y];
  int isf32 = *flag;
  for (int i = blockIdx.x*256 + threadIdx.x; i < cd.n; i += gridDim.x*256){
    cd.dst[i] = isf32 ? ((const float*)cd.src)[i] : b2f(((const ushort_t*)cd.src)[i]);
  }
}

// --- LDS-tiled weight transpose: src (K x M row-major) -> dst (Mpad x Kpad) --
// (Bl low-order output retired round 9 -- only the bf16-high part is stored.)
struct TDesc { const void* src; ushort_t* dh; int K; int M; int Kpad; int Mpad; int eoff; };
struct TDescArr { TDesc d[37]; };
__global__ __launch_bounds__(256) void transpose_all(TDescArr ta, const int* __restrict__ flag){
  TDesc td = ta.d[blockIdx.z];
  int k0 = blockIdx.x*32, m0 = blockIdx.y*32;
  if (k0 >= td.Kpad || m0 >= td.Mpad) return;
  int isf32 = *flag;
  __shared__ float lds[32*33];
  int tx = threadIdx.x & 31, ty = threadIdx.x >> 5;
  #pragma unroll
  for (int r = 0; r < 4; ++r){
    int kl = ty + r*8;
    int k = k0 + kl, mm = m0 + tx;
    float x = 0.f;
    if (k < td.K && mm < td.M){
      size_t si = (size_t)td.eoff + (size_t)k*td.M + mm;
      x = isf32 ? ((const float*)td.src)[si] : b2f(((const ushort_t*)td.src)[si]);
    }
    lds[kl*33 + tx] = x;
  }
  __syncthreads();
  #pragma unroll
  for (int r = 0; r < 4; ++r){
    int nl = ty + r*8;
    int n = m0 + nl, k = k0 + tx;
    if (n < td.Mpad && k < td.Kpad){
      float x = lds[tx*33 + nl];
      size_t di = (size_t)n*td.Kpad + k;
      td.dh[di] = f2b(x);
    }
  }
}

// ---- fused per-edge setup: spherical harmonics + RBF projections + CSR hist.
// Round 13: r_all written as 6 float4 stores (base 16B-aligned).
__global__ __launch_bounds__(128) void edge_all_kernel(
    const float* __restrict__ pos,
    const int* __restrict__ esrc, const int* __restrict__ edst,
    const float* __restrict__ degWr,
    const float* __restrict__ b0Wr, const float* __restrict__ bmWr,
    const float* __restrict__ bfWr,
    float* __restrict__ sh_out, float* __restrict__ t9,
    float* __restrict__ r_all, int* __restrict__ counts){
  __shared__ float w9L[128*9];
  __shared__ float w24L[128*24];
  int t = threadIdx.x;
  for (int i = t; i < 128*9; i += 128)  w9L[i]  = degWr[i];
  for (int i = t; i < 128*24; i += 128){
    int k = i / 24, o = i - k*24;
    int slot = o >> 2, h = o & 3;
    const float* Wr = (slot == 0) ? b0Wr : ((slot <= 4) ? bmWr + (size_t)(slot-1)*512 : bfWr);
    w24L[i] = Wr[k*4+h];
  }
  __syncthreads();
  int e = blockIdx.x*128 + t; if (e >= NE) return;
  int s = esrc[e], d = edst[e];
  atomicAdd(&counts[d], 1);
  float x = pos[s*3+0] - pos[d*3+0];
  float y = pos[s*3+1] - pos[d*3+1];
  float z = pos[s*3+2] - pos[d*3+2];
  float dd = sqrtf(x*x + y*y + z*z + 1e-12f);
  float ix = x/dd, iy = y/dd, iz = z/dd;
  const float s3 = 1.7320508075688772f, s15 = 3.872983346207417f, s5 = 2.23606797749979f;
  float sh[9];
  sh[0] = 1.f; sh[1] = s3*ix; sh[2] = s3*iy; sh[3] = s3*iz;
  sh[4] = s15*ix*iy; sh[5] = s15*iy*iz; sh[6] = 0.5f*s5*(3.f*iz*iz - 1.f);
  sh[7] = s15*ix*iz; sh[8] = 0.5f*s15*(ix*ix - iy*iy);
  #pragma unroll
  for (int j = 0; j < 9; ++j) sh_out[(size_t)e*9+j] = sh[j];
  float t9a[9], ga[24];
  #pragma unroll
  for (int j = 0; j < 9; ++j) t9a[j] = 0.f;
  #pragma unroll
  for (int o = 0; o < 24; ++o) ga[o] = 0.f;
  for (int k = 0; k < 128; ++k){
    float c = (float)k * (5.0f/127.0f);
    float u = (dd - c) * (128.0f/5.0f);
    float rb = __expf(-0.5f*u*u);
    const float* w9  = w9L + k*9;
    const float* w24 = w24L + k*24;
    #pragma unroll
    for (int j = 0; j < 9; ++j) t9a[j] += rb*w9[j];
    #pragma unroll
    for (int o = 0; o < 24; ++o) ga[o] += rb*w24[o];
  }
  #pragma unroll
  for (int j = 0; j < 9; ++j) t9[(size_t)e*9+j] = sh[j]*silu_f(t9a[j]);
  #pragma unroll
  for (int slot = 0; slot < 6; ++slot){
    floatx4 rv;
    rv[0] = silu_f(ga[slot*4+0]);
    rv[1] = silu_f(ga[slot*4+1]);
    rv[2] = silu_f(ga[slot*4+2]);
    rv[3] = silu_f(ga[slot*4+3]);
    *(floatx4*)&r_all[((size_t)slot*NE + e)*4] = rv;
  }
}

// ---------------- CSR build ----------------
__global__ __launch_bounds__(1024) void scan_kernel(const int* __restrict__ counts,
                                                    int* rowptr, int* cursor,
                                                    float* __restrict__ gsum){
  __shared__ int s[1024];
  int t = threadIdx.x;
  if (t < 64) gsum[t] = 0.f;
  int c0 = counts[2*t], c1 = counts[2*t+1];
  s[t] = c0 + c1;
  __syncthreads();
  for (int off = 1; off < 1024; off <<= 1){
    int v = (t >= off) ? s[t-off] : 0;
    __syncthreads();
    s[t] += v;
    __syncthreads();
  }
  int excl = s[t] - (c0 + c1);
  rowptr[2*t]   = excl;       cursor[2*t]   = excl;
  rowptr[2*t+1] = excl + c0;  cursor[2*t+1] = excl + c0;
  if (t == 1023) rowptr[2048] = s[1023];
}
__global__ void scatter_kernel(const int* __restrict__ edst, int* cursor, int* perm){
  int e = blockIdx.x*256 + threadIdx.x; if (e >= NE) return;
  int p = atomicAdd(&cursor[edst[e]], 1);
  perm[p] = e;
}

// -- inj = atom_table[node_atom] + (sum_e t9) @ degWsh / 16; also zeroes z0 ---
// Round 13: float4 over DINJ (rows 960B-aligned) + float4 z0 zeroing.
__global__ __launch_bounds__(64) void inj_kernel(const float* __restrict__ t9,
    const int* __restrict__ rowptr, const int* __restrict__ perm,
    const int* __restrict__ node_atom, const float* __restrict__ atom_table,
    const float* __restrict__ degWsh, float* __restrict__ inj,
    float* __restrict__ z0){
  int i = blockIdx.x; int lane = threadIdx.x;
  int b = rowptr[i], e = rowptr[i+1];
  floatx4* z4 = (floatx4*)(z0 + (size_t)i*480);
  #pragma unroll
  for (int v = lane; v < 120; v += 64) z4[v] = (floatx4){0,0,0,0};
  float T[9];
  #pragma unroll
  for (int j = 0; j < 9; ++j) T[j] = 0.f;
  for (int idx = b; idx < e; ++idx){
    int ed = perm[idx];
    #pragma unroll
    for (int j = 0; j < 9; ++j) T[j] += t9[(size_t)ed*9+j];
  }
  int a = node_atom[i];
  if (lane < 60){
    const floatx4* tb4 = (const floatx4*)(atom_table + (size_t)a*DINJ);
    const floatx4* w4  = (const floatx4*)degWsh;
    floatx4 s = {0,0,0,0};
    #pragma unroll
    for (int j = 0; j < 9; ++j){
      floatx4 wv = w4[j*60 + lane];
      s[0] += T[j]*wv[0]; s[1] += T[j]*wv[1];
      s[2] += T[j]*wv[2]; s[3] += T[j]*wv[3];
    }
    floatx4 tv = tb4[lane];
    floatx4 o;
    o[0] = tv[0] + s[0]*(1.0f/16.0f);
    o[1] = tv[1] + s[1]*(1.0f/16.0f);
    o[2] = tv[2] + s[2]*(1.0f/16.0f);
    o[3] = tv[3] + s[3]*(1.0f/16.0f);
    *(floatx4*)(inj + (size_t)i*DINJ + lane*4) = o;
  }
}

// ------- LayerNorm: one wave per row, 4 rows per block. ----------------------
__global__ __launch_bounds__(256) void ln_kernel(const float* __restrict__ in, int D,
                                                 int Kpad, ushort_t* __restrict__ oh){
  int i = blockIdx.x*4 + (threadIdx.x >> 6);
  int lane = threadIdx.x & 63;
  const float4* row = (const float4*)(in + (size_t)i*D);
  int nv = D >> 2;
  float4 x0 = row[lane];
  bool h1 = (lane + 64)  < nv;
  bool h2 = (lane + 128) < nv;
  float4 x1 = {0,0,0,0}; if (h1) x1 = row[lane+64];
  float4 x2 = {0,0,0,0}; if (h2) x2 = row[lane+128];
  float s  = x0.x+x0.y+x0.z+x0.w + x1.x+x1.y+x1.z+x1.w + x2.x+x2.y+x2.z+x2.w;
  float sq = x0.x*x0.x+x0.y*x0.y+x0.z*x0.z+x0.w*x0.w
           + x1.x*x1.x+x1.y*x1.y+x1.z*x1.z+x1.w*x1.w
           + x2.x*x2.x+x2.y*x2.y+x2.z*x2.z+x2.w*x2.w;
  s = wredsum(s); sq = wredsum(sq);
  float mu = s / (float)D;
  float var = fmaxf(sq / (float)D - mu*mu, 0.f);
  float rs = rsqrtf(var + 1e-6f);
  ushort_t* ohrow = oh + (size_t)i*Kpad;
  auto st = [&](int v, float4 x){
    ushortx4 o;
    o[0] = f2b((x.x-mu)*rs); o[1] = f2b((x.y-mu)*rs);
    o[2] = f2b((x.z-mu)*rs); o[3] = f2b((x.w-mu)*rs);
    *(ushortx4*)(ohrow + (size_t)v*4) = o;
  };
  st(lane, x0);
  if (h1) st(lane+64, x1);
  if (h2) st(lane+128, x2);
  for (int d = D + lane; d < Kpad; d += 64) ohrow[d] = 0;
}

// ------- LayerNorm over concat [z(480) | inj(240)] -> 736-padded bf16 --------
__global__ __launch_bounds__(256) void ln_cat_kernel(const float* __restrict__ z,
    const float* __restrict__ inj, ushort_t* __restrict__ oh){
  int i = blockIdx.x*4 + (threadIdx.x >> 6);
  int lane = threadIdx.x & 63;
  const float4* zr = (const float4*)(z + (size_t)i*480);     // 120 float4
  const float4* ir = (const float4*)(inj + (size_t)i*240);   // 60 float4
  auto ld = [&](int v) -> float4 { return (v < 120) ? zr[v] : ir[v-120]; };
  float4 x0 = ld(lane);
  float4 x1 = ld(lane + 64);
  bool h2 = (lane + 128) < 180;
  float4 x2 = {0,0,0,0}; if (h2) x2 = ld(lane+128);
  float s  = x0.x+x0.y+x0.z+x0.w + x1.x+x1.y+x1.z+x1.w + x2.x+x2.y+x2.z+x2.w;
  float sq = x0.x*x0.x+x0.y*x0.y+x0.z*x0.z+x0.w*x0.w
           + x1.x*x1.x+x1.y*x1.y+x1.z*x1.z+x1.w*x1.w
           + x2.x*x2.x+x2.y*x2.y+x2.z*x2.z+x2.w*x2.w;
  s = wredsum(s); sq = wredsum(sq);
  float mu = s * (1.0f/720.0f);
  float var = fmaxf(sq * (1.0f/720.0f) - mu*mu, 0.f);
  float rs = rsqrtf(var + 1e-6f);
  ushort_t* ohrow = oh + (size_t)i*736;
  auto st = [&](int v, float4 x){
    ushortx4 o;
    o[0] = f2b((x.x-mu)*rs); o[1] = f2b((x.y-mu)*rs);
    o[2] = f2b((x.z-mu)*rs); o[3] = f2b((x.w-mu)*rs);
    *(ushortx4*)(ohrow + (size_t)v*4) = o;
  };
  st(lane, x0);
  st(lane+64, x1);
  if (h2) st(lane+128, x2);
  for (int d = 720 + lane; d < 736; d += 64) ohrow[d] = 0;
}

// ---- shared MFMA ring: compile-time COUNT/BASE keep the ring in registers ---
struct Frag { short8 A0, A1, B0h, B1h; };
template<int COUNT, int BASE>
__device__ __forceinline__ void mfma_ring(
    const ushort_t* __restrict__ A, size_t a0, size_t a1,
    const ushort_t* __restrict__ BTh, size_t b0, size_t b1,
    floatx4& acc00, floatx4& acc01, floatx4& acc10, floatx4& acc11){
  constexpr int DEPTH = 4;
  auto loadF = [&](int s) -> Frag {
    Frag f;
    size_t o = (size_t)(BASE + s)*32;
    f.A0  = *(const short8*)(A   + a0 + o);
    f.A1  = *(const short8*)(A   + a1 + o);
    f.B0h = *(const short8*)(BTh + b0 + o);
    f.B1h = *(const short8*)(BTh + b1 + o);
    return f;
  };
  Frag ring[DEPTH];
  #pragma unroll
  for (int d = 0; d < DEPTH; ++d) ring[d] = loadF(d < COUNT ? d : COUNT-1);
  #pragma unroll
  for (int s = 0; s < COUNT; ++s){
    Frag cur = ring[s % DEPTH];
    if (s + DEPTH < COUNT) ring[s % DEPTH] = loadF(s + DEPTH);
    acc00 = __builtin_amdgcn_mfma_f32_16x16x32_bf16(cur.A0, cur.B0h, acc00, 0, 0, 0);
    acc01 = __builtin_amdgcn_mfma_f32_16x16x32_bf16(cur.A0, cur.B1h, acc01, 0, 0, 0);
    acc10 = __builtin_amdgcn_mfma_f32_16x16x32_bf16(cur.A1, cur.B0h, acc10, 0, 0, 0);
    acc11 = __builtin_amdgcn_mfma_f32_16x16x32_bf16(cur.A1, cur.B1h, acc11, 0, 0, 0);
  }
}

// -- MFMA GEMM: C = A * Bh^T (Bl split fully retired round 9). ----------------
// flags: 1=silu, 2=add residual, 4=bf16 out, 8=residual is concat(R 480, R2 240)
//        16=qkv split-out: col<960 -> Cf (f32, ld 960), col>=960 -> Cb (bf16, ld 480)
template<int KPAD>
__global__ __launch_bounds__(256) void gemm_bt(
    const ushort_t* __restrict__ A, const ushort_t* __restrict__ BTh,
    int N, int ldc,
    float* __restrict__ Cf, ushort_t* __restrict__ Cb,
    const float* __restrict__ R, const float* __restrict__ R2, int flags){
  int bx, by; xcd_swizzle(bx, by);
  int lane = threadIdx.x & 63, wave = threadIdx.x >> 6;
  int row0 = by*64 + (wave>>1)*32;
  int col0 = bx*64 + (wave&1)*32;
  int m = lane & 15, q4 = lane >> 4;
  size_t a0 = (size_t)(row0+m)*KPAD + q4*8;
  size_t a1 = a0 + (size_t)16*KPAD;
  size_t b0 = (size_t)(col0+m)*KPAD + q4*8;
  size_t b1 = b0 + (size_t)16*KPAD;
  floatx4 acc00 = {0,0,0,0}, acc01 = {0,0,0,0}, acc10 = {0,0,0,0}, acc11 = {0,0,0,0};
  constexpr int steps = KPAD >> 5;
  mfma_ring<steps, 0>(A, a0, a1, BTh, b0, b1, acc00, acc01, acc10, acc11);
  #pragma unroll
  for (int rr = 0; rr < 2; ++rr){
    #pragma unroll
    for (int cc = 0; cc < 2; ++cc){
      int col = col0 + cc*16 + m;
      if (col >= N) continue;
      floatx4 acc = rr ? (cc ? acc11 : acc10) : (cc ? acc01 : acc00);
      int rowb = row0 + rr*16 + q4*4;
      #pragma unroll
      for (int r = 0; r < 4; ++r){
        int row = rowb + r;
        float v = acc[r];
        if (flags & 16){
          if (col < 960) Cf[(size_t)row*960 + col] = v;
          else           Cb[(size_t)row*480 + (col - 960)] = f2b(v);
          continue;
        }
        size_t idx = (size_t)row*ldc + col;
        if (flags & 2){
          if (flags & 8)
            v += (col < 480) ? R[(size_t)row*480 + col] : R2[(size_t)row*240 + (col-480)];
          else
            v += R[idx];
        }
        if (flags & 1) v = silu_f(v);
        if (flags & 4) Cb[idx] = f2b(v);
        else           Cf[idx] = v;
      }
    }
  }
}

// -- 8-wave split-K variant for small-N GEMMs. ---
template<int KPAD>
__global__ __launch_bounds__(512) void gemm_bt8(
    const ushort_t* __restrict__ A, const ushort_t* __restrict__ BTh,
    int N, int ldc,
    float* __restrict__ Cf, ushort_t* __restrict__ Cb,
    const float* __restrict__ R, const float* __restrict__ R2, int flags){
  __shared__ float accL[4][4][256];
  int bx, by; xcd_swizzle(bx, by);
  int lane = threadIdx.x & 63, wave = threadIdx.x >> 6;
  int half = wave >> 2, w4 = wave & 3;
  int row0 = by*64 + (w4>>1)*32;
  int col0 = bx*64 + (w4&1)*32;
  int m = lane & 15, q4 = lane >> 4;
  size_t a0 = (size_t)(row0+m)*KPAD + q4*8;
  size_t a1 = a0 + (size_t)16*KPAD;
  size_t b0 = (size_t)(col0+m)*KPAD + q4*8;
  size_t b1 = b0 + (size_t)16*KPAD;
  floatx4 acc00 = {0,0,0,0}, acc01 = {0,0,0,0}, acc10 = {0,0,0,0}, acc11 = {0,0,0,0};
  constexpr int steps = KPAD >> 5;
  constexpr int S0 = (steps + 1) >> 1;
  constexpr int S1 = steps - S0;
  if (half == 0)
    mfma_ring<S0, 0 >(A, a0, a1, BTh, b0, b1, acc00, acc01, acc10, acc11);
  else
    mfma_ring<S1, S0>(A, a0, a1, BTh, b0, b1, acc00, acc01, acc10, acc11);
  if (half == 1){
    *(floatx4*)&accL[w4][0][lane*4] = acc00;
    *(floatx4*)&accL[w4][1][lane*4] = acc01;
    *(floatx4*)&accL[w4][2][lane*4] = acc10;
    *(floatx4*)&accL[w4][3][lane*4] = acc11;
  }
  __syncthreads();
  if (half == 1) return;
  acc00 += *(const floatx4*)&accL[w4][0][lane*4];
  acc01 += *(const floatx4*)&accL[w4][1][lane*4];
  acc10 += *(const floatx4*)&accL[w4][2][lane*4];
  acc11 += *(const floatx4*)&accL[w4][3][lane*4];
  #pragma unroll
  for (int rr = 0; rr < 2; ++rr){
    #pragma unroll
    for (int cc = 0; cc < 2; ++cc){
      int col = col0 + cc*16 + m;
      if (col >= N) continue;
      floatx4 acc = rr ? (cc ? acc11 : acc10) : (cc ? acc01 : acc00);
      int rowb = row0 + rr*16 + q4*4;
      #pragma unroll
      for (int r = 0; r < 4; ++r){
        int row = rowb + r;
        float v = acc[r];
        size_t idx = (size_t)row*ldc + col;
        if (flags & 2){
          if (flags & 8)
            v += (col < 480) ? R[(size_t)row*480 + col] : R2[(size_t)row*240 + (col-480)];
          else
            v += R[idx];
        }
        if (flags & 1) v = silu_f(v);
        if (flags & 4) Cb[idx] = f2b(v);
        else           Cf[idx] = v;
      }
    }
  }
}

// ------- fused per-node attention: logits + softmax + aggregation ------------
// qk: f32 [NN][960] (q 0..479, k 480..959); vb: bf16 [NN][480]
// K stays f32 (round 6); sh/r staged to LDS (round 8); 2-lane logit split
// (round 5; 4-lane and V-unroll variants both regressed, rounds 10/14).
// qL staged with float4 (round 13).
__global__ __launch_bounds__(256) void node_attn_kernel(
    const float* __restrict__ qk, const ushort_t* __restrict__ vb,
    const float* __restrict__ sh,
    const float* __restrict__ Wsh, const float* __restrict__ r_slot,
    const int* __restrict__ rowptr, const int* __restrict__ perm,
    const int* __restrict__ esrc, ushort_t* __restrict__ aggh){
  int i = blockIdx.x; int t = threadIdx.x;
  int lane = t & 63, w = t >> 6;
  int b = rowptr[i]; int deg = min(rowptr[i+1] - b, MAXDEG);
  __shared__ float qL[480];
  __shared__ float PqL[36];
  __shared__ float logitL[MAXDEG*4];
  __shared__ float rL[MAXDEG*4];
  __shared__ float shL[MAXDEG*9];
  __shared__ int eL[MAXDEG], srcL[MAXDEG];
  __shared__ float S[36];
  __shared__ float mxs[4], dens[4];
  if (t < 120) ((float4*)qL)[t] = ((const float4*)(qk + (size_t)i*960))[t];
  for (int idx = t; idx < deg; idx += 256){
    int e = perm[b+idx];
    eL[idx] = e;
    srcL[idx] = esrc[e];
  }
  __syncthreads();
  // stage sh rows (deg x 9) and r gates (deg x 4) into LDS
  for (int j = t; j < deg*9; j += 256){
    int idx = j/9;
    shL[j] = sh[(size_t)eL[idx]*9 + (j - idx*9)];
  }
  for (int j = t; j < deg*4; j += 256){
    rL[j] = r_slot[(size_t)eL[j>>2]*4 + (j&3)];
  }
  // PqL[h*9+j] = q_h . Wsh[j, h*120..]; 4 lanes per output, quad shuffle reduce
  if (t < 144){
    int o = t >> 2;
    int h = o/9, j = o - h*9;
    int kq = (t & 3)*30;
    const float* ws = Wsh + (size_t)j*DEMB + h*120 + kq;
    const float* qh = qL + h*120 + kq;
    float p = 0.f;
    #pragma unroll
    for (int k = 0; k < 30; ++k) p += qh[k]*ws[k];
    p += __shfl_xor(p, 1, 64);
    p += __shfl_xor(p, 2, 64);
    if ((t & 3) == 0) PqL[o] = p;
  }
  __syncthreads();
  const float inv = 0.091287092917527686f;
  // logits: 2 lanes per (edge,head) -> 32 edges/pass, 15 float4 each, pair-reduce
  for (int base = 0; base < deg; base += 32){
    int idx = base + (t >> 3);
    if (idx < deg){
      int h = (t >> 1) & 3;
      int hs = t & 1;
      int s = srcL[idx];
      const float4* kk = (const float4*)(qk + (size_t)s*960 + 480 + h*120) + hs*15;
      const float4* qq = (const float4*)(qL + h*120) + hs*15;
      float p = 0.f;
      #pragma unroll
      for (int it = 0; it < 15; ++it){
        float4 a = qq[it], bb = kk[it];
        p += a.x*bb.x + a.y*bb.y + a.z*bb.z + a.w*bb.w;
      }
      p += __shfl_xor(p, 1, 64);
      if (hs == 0){
        float mmq = 0.f;
        const float* she = shL + idx*9;
        #pragma unroll
        for (int j = 0; j < 9; ++j) mmq += she[j]*PqL[h*9+j];
        logitL[idx*4+h] = rL[idx*4+h]*(p + mmq)*inv;
      }
    }
  }
  __syncthreads();
  float mx = -1e30f;
  for (int idx = lane; idx < deg; idx += 64) mx = fmaxf(mx, logitL[idx*4+w]);
  #pragma unroll
  for (int o = 32; o > 0; o >>= 1) mx = fmaxf(mx, __shfl_xor(mx, o, 64));
  if (deg == 0) mx = 0.f;
  float den = 0.f;
  for (int idx = lane; idx < deg; idx += 64) den += __expf(logitL[idx*4+w]-mx);
  den = wredsum(den) + 1e-9f;
  if (lane == 0){ mxs[w] = mx; dens[w] = den; }
  __syncthreads();
  for (int j = t; j < deg*4; j += 256){
    int h = j & 3;
    logitL[j] = __expf(logitL[j]-mxs[h]) / dens[h] * rL[j];
  }
  __syncthreads();
  float a0 = 0.f, a1 = 0.f;
  int d0 = 2*t, h2 = d0/120;
  if (t >= 240){
    for (int o = t - 240; o < 36; o += 16){
      int h = o/9, j = o - h*9;
      float a = 0.f;
      for (int idx = 0; idx < deg; ++idx)
        a += logitL[idx*4+h]*shL[idx*9+j];
      S[o] = a;
    }
  } else {
    for (int idx = 0; idx < deg; ++idx){
      float wgt = logitL[idx*4+h2];
      unsigned vv = *(const unsigned*)(vb + (size_t)srcL[idx]*480 + d0);
      a0 += wgt*b2f((ushort_t)(vv & 0xFFFFu));
      a1 += wgt*b2f((ushort_t)(vv >> 16));
    }
  }
  __syncthreads();
  if (t < 240){
    float mm0 = 0.f, mm1 = 0.f;
    #pragma unroll
    for (int j = 0; j < 9; ++j){
      mm0 += S[h2*9+j]*Wsh[j*DEMB + d0];
      mm1 += S[h2*9+j]*Wsh[j*DEMB + d0 + 1];
    }
    aggh[(size_t)i*DEMB + d0]     = f2b(a0 + mm0);
    aggh[(size_t)i*DEMB + d0 + 1] = f2b(a1 + mm1);
  }
}

// ---------------- head ----------------
__global__ __launch_bounds__(256) void head_dot_kernel(const ushort_t* __restrict__ g1h,
    const float* __restrict__ hW2, const int* __restrict__ batch, float* gsum){
  int i = blockIdx.x*4 + (threadIdx.x >> 6);
  int lane = threadIdx.x & 63;
  const ushortx4* gr = (const ushortx4*)(g1h + (size_t)i*DFEAT);
  const float4* wv = (const float4*)hW2;
  float s = 0.f;
  #pragma unroll
  for (int v = 0; v < 2; ++v){
    int idx = lane + v*64;
    ushortx4 g = gr[idx];
    float4 ww = wv[idx];
    s += b2f(g[0])*ww.x + b2f(g[1])*ww.y + b2f(g[2])*ww.z + b2f(g[3])*ww.w;
  }
  s = wredsum(s);
  if (lane == 0) atomicAdd(&gsum[batch[i]], s);
}
__global__ void finalize_kernel(const float* __restrict__ gsum,
                                const int* __restrict__ flag, void* out){
  int g = threadIdx.x;
  if (g < NG){
    float v = gsum[g] * 0.17677669529663687f; // 1/sqrt(32)
    if (*flag) ((float*)out)[g] = v;
    else       ((ushort_t*)out)[g] = f2b(v);
  }
}

// =====================================================================
extern "C" void kernel_launch(void* const* d_in, const int* in_sizes, int n_in,
                              void* d_out, int out_size, void* d_ws, size_t ws_size,
                              hipStream_t stream) {
  (void)in_sizes; (void)n_in; (void)out_size; (void)ws_size;
  const void* pos        = d_in[0];
  const int*  node_atom  = (const int*)d_in[1];
  const int*  esrc       = (const int*)d_in[2];
  const int*  edst       = (const int*)d_in[3];
  const int*  batch      = (const int*)d_in[4];
  const void* atom_table = d_in[5];
  const void* degWr      = d_in[6];
  const void* degWsh     = d_in[7];
  const void* b0_Wq  = d_in[8];
  const void* b0_Wk  = d_in[9];
  const void* b0_Wv  = d_in[10];
  const void* b0_Wsh = d_in[11];
  const void* b0_Wr  = d_in[12];
  const void* b0_Wo  = d_in[13];
  const void* b0_F1  = d_in[14];
  const void* b0_F2  = d_in[15];
  const void* bm_Wq  = d_in[16];
  const void* bm_Wk  = d_in[17];
  const void* bm_Wv  = d_in[18];
  const void* bm_Wsh = d_in[19];
  const void* bm_Wr  = d_in[20];
  const void* bm_Wo  = d_in[21];
  const void* bm_F1  = d_in[22];
  const void* bm_F2  = d_in[23];
  const void* bf_Wq  = d_in[24];
  const void* bf_Wk  = d_in[25];
  const void* bf_Wv  = d_in[26];
  const void* bf_Wsh = d_in[27];
  const void* bf_Wr  = d_in[28];
  const void* bf_Wo  = d_in[29];
  const void* bf_F1  = d_in[30];
  const void* bf_F2  = d_in[31];
  const void* hW1    = d_in[32];
  const void* hW2    = d_in[33];

  char* bws = (char*)d_ws;
  size_t off = 0;
  auto alloc = [&](size_t bytes) -> void* {
    void* p = bws + off;
    off += (bytes + 255) & ~(size_t)255;
    return p;
  };
  int* dflag   = (int*)alloc(256);
  float* sh_f  = (float*)alloc((size_t)NE*9*4);
  float* t9    = (float*)alloc((size_t)NE*9*4);
  int* counts  = (int*)alloc(2048*4);
  int* rowptr  = (int*)alloc(2049*4);
  int* cursor  = (int*)alloc(2048*4);
  int* perm    = (int*)alloc((size_t)NE*4);
  float* injb  = (float*)alloc((size_t)NN*DINJ*4);
  float* zA    = (float*)alloc((size_t)NN*512*4);
  float* zB    = (float*)alloc((size_t)NN*512*4);
  ushort_t* xlnh = (ushort_t*)alloc((size_t)NN*736*2);
  float* qkf   = (float*)alloc((size_t)NN*960*4);
  ushort_t* vbuf = (ushort_t*)alloc((size_t)NN*480*2);
  float* r_all = (float*)alloc((size_t)6*NE*4*4);
  ushort_t* aggh = (ushort_t*)alloc((size_t)NN*DEMB*2);
  float* ybuf  = (float*)alloc((size_t)NN*720*4);
  ushort_t* h1h = (ushort_t*)alloc((size_t)NN*DEMB*2);
  ushort_t* g1h = (ushort_t*)alloc((size_t)NN*DFEAT*2);
  float* gsum  = (float*)alloc(64*4);

  float* pos_c    = (float*)alloc((size_t)NN*3*4);
  float* atom_c   = (float*)alloc((size_t)64*DINJ*4);
  float* degWr_c  = (float*)alloc((size_t)128*9*4);
  float* degWsh_c = (float*)alloc((size_t)9*DINJ*4);
  float* b0_Wsh_c = (float*)alloc((size_t)9*480*4);
  float* b0_Wr_c  = (float*)alloc((size_t)128*4*4);
  float* bm_Wsh_c = (float*)alloc((size_t)4*9*480*4);
  float* bm_Wr_c  = (float*)alloc((size_t)4*128*4*4);
  float* bf_Wsh_c = (float*)alloc((size_t)9*480*4);
  float* bf_Wr_c  = (float*)alloc((size_t)128*4*4);
  float* hW2_c    = (float*)alloc((size_t)512*4);

  auto allocW = [&](size_t elems) -> ushort_t* {
    return (ushort_t*)alloc(elems*2);
  };
  ushort_t *b0_qkvTh = allocW((size_t)1472*736);
  ushort_t *b0_WoTh  = allocW((size_t)768*480);
  ushort_t *b0_F1Th  = allocW((size_t)512*736);
  ushort_t *b0_F2Th  = allocW((size_t)512*480);
  ushort_t *bm_qkvTh[4], *bm_WoTh[4], *bm_F1Th[4], *bm_F2Th[4];
  for (int i = 0; i < 4; ++i){
    bm_qkvTh[i] = allocW((size_t)1472*480);
    bm_WoTh[i]  = allocW((size_t)512*480);
    bm_F1Th[i]  = allocW((size_t)512*480);
    bm_F2Th[i]  = allocW((size_t)512*480);
  }
  ushort_t *bf_qkvTh = allocW((size_t)1472*480);
  ushort_t *bf_WoTh  = allocW((size_t)512*480);
  ushort_t *bf_F1Th  = allocW((size_t)512*480);
  ushort_t *bf_F2Th  = allocW((size_t)512*480);
  ushort_t *hW1Th    = allocW((size_t)512*512);

  detect_kernel<<<1, 256, 0, stream>>>((const ushort_t*)atom_table, dflag, counts);

  CDescArr ca;
  int ci = 0;
  auto addC = [&](const void* s, float* d, int n){
    ca.d[ci].src = s; ca.d[ci].dst = d; ca.d[ci].n = n; ++ci;
  };
  addC(pos, pos_c, NN*3);
  addC(atom_table, atom_c, 64*DINJ);
  addC(degWr, degWr_c, 128*9);
  addC(degWsh, degWsh_c, 9*DINJ);
  addC(b0_Wsh, b0_Wsh_c, 9*480);
  addC(b0_Wr, b0_Wr_c, 128*4);
  addC(bm_Wsh, bm_Wsh_c, 4*9*480);
  addC(bm_Wr, bm_Wr_c, 4*128*4);
  addC(bf_Wsh, bf_Wsh_c, 9*480);
  addC(bf_Wr, bf_Wr_c, 128*4);
  addC(hW2, hW2_c, 512);
  convert_inputs<<<dim3(8, 11), 256, 0, stream>>>(ca, dflag);

  TDescArr ta;
  int ti = 0;
  auto addT = [&](const void* s, ushort_t* dh, int K, int M,
                  int Kp, int Mp, int rowoff, int eo){
    ta.d[ti].src = s;
    ta.d[ti].dh = dh + (size_t)rowoff*Kp;
    ta.d[ti].K = K; ta.d[ti].M = M; ta.d[ti].Kpad = Kp; ta.d[ti].Mpad = Mp;
    ta.d[ti].eoff = eo; ++ti;
  };
  addT(b0_Wq, b0_qkvTh, 720, 480, 736, 480, 0,   0);
  addT(b0_Wk, b0_qkvTh, 720, 480, 736, 480, 480, 0);
  addT(b0_Wv, b0_qkvTh, 720, 480, 736, 512, 960, 0);
  addT(b0_Wo, b0_WoTh,  480, 720, 480, 768, 0,   0);
  addT(b0_F1, b0_F1Th,  720, 480, 736, 512, 0,   0);
  addT(b0_F2, b0_F2Th,  480, 480, 480, 512, 0,   0);
  for (int i = 0; i < 4; ++i){
    int eo = i*480*480;
    addT(bm_Wq, bm_qkvTh[i], 480, 480, 480, 480, 0,   eo);
    addT(bm_Wk, bm_qkvTh[i], 480, 480, 480, 480, 480, eo);
    addT(bm_Wv, bm_qkvTh[i], 480, 480, 480, 512, 960, eo);
    addT(bm_Wo, bm_WoTh[i],  480, 480, 480, 512, 0,   eo);
    addT(bm_F1, bm_F1Th[i],  480, 480, 480, 512, 0,   eo);
    addT(bm_F2, bm_F2Th[i],  480, 480, 480, 512, 0,   eo);
  }
  addT(bf_Wq, bf_qkvTh, 480, 480, 480, 480, 0,   0);
  addT(bf_Wk, bf_qkvTh, 480, 480, 480, 480, 480, 0);
  addT(bf_Wv, bf_qkvTh, 480, 480, 480, 512, 960, 0);
  addT(bf_Wo, bf_WoTh,  480, 480, 480, 512, 0,   0);
  addT(bf_F1, bf_F1Th,  480, 480, 480, 512, 0,   0);
  addT(bf_F2, bf_F2Th,  480, 512, 480, 512, 0,   0);
  addT(hW1,   hW1Th,    512, 512, 512, 512, 0,   0);
  transpose_all<<<dim3(23, 24, 37), 256, 0, stream>>>(ta, dflag);

  edge_all_kernel<<<NE/128, 128, 0, stream>>>(pos_c, esrc, edst, degWr_c,
                                              b0_Wr_c, bm_Wr_c, bf_Wr_c,
                                              sh_f, t9, r_all, counts);

  scan_kernel<<<1, 1024, 0, stream>>>(counts, rowptr, cursor, gsum);
  scatter_kernel<<<NE/256, 256, 0, stream>>>(edst, cursor, perm);

  inj_kernel<<<NN, 64, 0, stream>>>(t9, rowptr, perm, node_atom, atom_c, degWsh_c,
                                    injb, zA);

  auto gemm = [&](const ushort_t* A, const ushort_t* BTh,
                  int N, int Npad, int Kp, int ldc,
                  float* Cf, ushort_t* Cb, const float* R, const float* R2,
                  int flags){
    dim3 g(Npad/64, 32);
    if (Npad <= 768){
      if (Kp == 480)
        gemm_bt8<480><<<g, 512, 0, stream>>>(A, BTh, N, ldc, Cf, Cb, R, R2, flags);
      else if (Kp == 512)
        gemm_bt8<512><<<g, 512, 0, stream>>>(A, BTh, N, ldc, Cf, Cb, R, R2, flags);
      else
        gemm_bt8<736><<<g, 512, 0, stream>>>(A, BTh, N, ldc, Cf, Cb, R, R2, flags);
      return;
    }
    if (Kp == 480)
      gemm_bt<480><<<g, 256, 0, stream>>>(A, BTh, N, ldc, Cf, Cb, R, R2, flags);
    else if (Kp == 512)
      gemm_bt<512><<<g, 256, 0, stream>>>(A, BTh, N, ldc, Cf, Cb, R, R2, flags);
    else
      gemm_bt<736><<<g, 256, 0, stream>>>(A, BTh, N, ldc, Cf, Cb, R, R2, flags);
  };

  struct BW {
    const float *Wsh, *r_slot;
    const ushort_t *qkvTh,*WoTh,*F1Th,*F2Th;
    int Din, Kpad, Dout; bool res;
  };
  auto run_block = [&](const BW& bw, const float* zin, const float* zinj, float* zout){
    if (zinj) ln_cat_kernel<<<NN/4, 256, 0, stream>>>(zin, zinj, xlnh);
    else      ln_kernel<<<NN/4, 256, 0, stream>>>(zin, bw.Din, bw.Kpad, xlnh);
    gemm(xlnh, bw.qkvTh, 1440, 1472, bw.Kpad, 960, qkf, vbuf, nullptr, nullptr, 16);
    node_attn_kernel<<<NN, 256, 0, stream>>>(qkf, vbuf, sh_f, bw.Wsh, bw.r_slot,
                                             rowptr, perm, esrc, aggh);
    int WoNpad = (bw.Din == 720) ? 768 : 512;
    gemm(aggh, bw.WoTh, bw.Din, WoNpad, 480, bw.Din,
         ybuf, nullptr, zin, zinj, zinj ? (2|8) : 2);
    ln_kernel<<<NN/4, 256, 0, stream>>>(ybuf, bw.Din, bw.Kpad, xlnh);
    gemm(xlnh, bw.F1Th, DEMB, 512, bw.Kpad, DEMB, nullptr, h1h, nullptr, nullptr, 1|4);
    gemm(h1h, bw.F2Th, bw.Dout, 512, 480, bw.Dout,
         zout, nullptr, bw.res ? ybuf : nullptr, nullptr, bw.res ? 2 : 0);
  };

  BW b0 = { b0_Wsh_c, r_all + (size_t)0*NE*4,
            b0_qkvTh, b0_WoTh, b0_F1Th, b0_F2Th, 720, 736, 480, false };
  BW bm[4];
  for (int i = 0; i < 4; ++i){
    bm[i] = { bm_Wsh_c + (size_t)i*9*480, r_all + (size_t)(1+i)*NE*4,
              bm_qkvTh[i], bm_WoTh[i], bm_F1Th[i], bm_F2Th[i],
              480, 480, 480, true };
  }
  BW bf = { bf_Wsh_c, r_all + (size_t)5*NE*4,
            bf_qkvTh, bf_WoTh, bf_F1Th, bf_F2Th, 480, 480, 512, false };

  float* z  = zA;
  float* z2 = zB;
  for (int iter = 0; iter < 2; ++iter){
    run_block(b0, z, injb, z2);
    { float* tmp = z; z = z2; z2 = tmp; }
    for (int i = 0; i < 4; ++i){
      run_block(bm[i], z, nullptr, z2);
      { float* tmp = z; z = z2; z2 = tmp; }
    }
  }
  run_block(bf, z, nullptr, z2);
  ln_kernel<<<NN/4, 256, 0, stream>>>(z2, DFEAT, DFEAT, xlnh);
  gemm(xlnh, hW1Th, DFEAT, 512, DFEAT, DFEAT, nullptr, g1h, nullptr, nullptr, 1|4);
  head_dot_kernel<<<NN/4, 256, 0, stream>>>(g1h, hW2_c, batch, gsum);
  finalize_kernel<<<1, 64, 0, stream>>>(gsum, dflag, d_out);
}